// Round 8
// baseline (50.537 us; speedup 1.0000x reference)
//
#include <hip/hip_runtime.h>

#define DD 2048
#define MHH 32

typedef _Float16 hf2 __attribute__((ext_vector_type(2)));

__device__ __forceinline__ unsigned pack_pair(float lo, float hi) {
    hf2 v;
    v.x = (_Float16)lo;
    v.y = (_Float16)hi;
    return __builtin_bit_cast(unsigned, v);
}

__device__ __forceinline__ hf2 rfl2(unsigned u) {
    u = __builtin_amdgcn_readfirstlane(u);     // force SGPR residency
    return __builtin_bit_cast(hf2, u);
}

__device__ __forceinline__ hf2 dup16(float x) {
    hf2 v;
    v.x = (_Float16)x;
    v.y = v.x;
    return v;
}

// ---- gemv: 4 rows per block (one wave per row), y = relu(W x + b) ----
__device__ __forceinline__ void gemv4_body(const float* __restrict__ W,
                                           const float* __restrict__ x,
                                           const float* __restrict__ b,
                                           float* __restrict__ y, int blk) {
    const int wave = threadIdx.x >> 6;
    const int lane = threadIdx.x & 63;
    const int row  = (blk << 2) + wave;
    const float* Wr = W + (size_t)row * DD;
    float acc = 0.f;
#pragma unroll
    for (int it = 0; it < 8; ++it) {
        const int col = ((it << 6) + lane) << 2;       // float4 index, coalesced
        const float4 w4 = *reinterpret_cast<const float4*>(Wr + col);
        const float4 x4 = *reinterpret_cast<const float4*>(x + col);
        acc = fmaf(w4.x, x4.x, acc);
        acc = fmaf(w4.y, x4.y, acc);
        acc = fmaf(w4.z, x4.z, acc);
        acc = fmaf(w4.w, x4.w, acc);
    }
#pragma unroll
    for (int off = 32; off > 0; off >>= 1)
        acc += __shfl_down(acc, off, 64);
    if (lane == 0) {
        const float v = acc + b[row];
        y[row] = fmaxf(v, 0.f);
    }
}

// ---- meta: one row of nW = bm2 + sum_m V2[m]*relu(u*A + w*B + P) ----
// f16-packed over m-pairs, f32 accumulation (v_dot2_f32_f16). Constants are
// pre-packed f16x2 pairs in cst: [0..15]=A [16..31]=B [32..47]=V2 [48..63]=C
// [64..79]=bm1. P = bm1 + ov*C computed in f16 (bm1 in VGPR -> one SGPR
// operand per pk_fma).
__device__ __forceinline__ void meta_row_body(const float* __restrict__ Wr,
                                              const float* __restrict__ inp,
                                              const float ov,
                                              const unsigned* __restrict__ cst,
                                              const float bias2,
                                              float* __restrict__ nWr) {
    const int col0 = threadIdx.x * 4;            // first half, coalesced float4
    const int col1 = (DD / 2) + threadIdx.x * 4; // second half
    const float4 w4a = *reinterpret_cast<const float4*>(Wr + col0);
    const float4 u4a = *reinterpret_cast<const float4*>(inp + col0);
    const float4 w4b = *reinterpret_cast<const float4*>(Wr + col1);
    const float4 u4b = *reinterpret_cast<const float4*>(inp + col1);

    const uint4* c16 = (const uint4*)cst;
    hf2 Ap[MHH / 2], Bp[MHH / 2], Vp[MHH / 2], Pp[MHH / 2];
#pragma unroll
    for (int j = 0; j < 4; ++j) {               // A: SGPR
        const uint4 t = c16[j];
        Ap[4 * j + 0] = rfl2(t.x); Ap[4 * j + 1] = rfl2(t.y);
        Ap[4 * j + 2] = rfl2(t.z); Ap[4 * j + 3] = rfl2(t.w);
    }
#pragma unroll
    for (int j = 0; j < 4; ++j) {               // B: SGPR
        const uint4 t = c16[4 + j];
        Bp[4 * j + 0] = rfl2(t.x); Bp[4 * j + 1] = rfl2(t.y);
        Bp[4 * j + 2] = rfl2(t.z); Bp[4 * j + 3] = rfl2(t.w);
    }
#pragma unroll
    for (int j = 0; j < 4; ++j) {               // V2: SGPR
        const uint4 t = c16[8 + j];
        Vp[4 * j + 0] = rfl2(t.x); Vp[4 * j + 1] = rfl2(t.y);
        Vp[4 * j + 2] = rfl2(t.z); Vp[4 * j + 3] = rfl2(t.w);
    }
    const hf2 ovd = dup16(ov);
#pragma unroll
    for (int j = 0; j < 4; ++j) {
        const uint4 tc = c16[12 + j];           // C (-> SGPR)
        const uint4 tb = c16[16 + j];           // bm1 (stays VGPR)
        const hf2 c0v = rfl2(tc.x), c1v = rfl2(tc.y), c2v = rfl2(tc.z), c3v = rfl2(tc.w);
        hf2 b0v = __builtin_bit_cast(hf2, tb.x);
        hf2 b1v = __builtin_bit_cast(hf2, tb.y);
        hf2 b2v = __builtin_bit_cast(hf2, tb.z);
        hf2 b3v = __builtin_bit_cast(hf2, tb.w);
        Pp[4 * j + 0] = __builtin_elementwise_fma(ovd, c0v, b0v);
        Pp[4 * j + 1] = __builtin_elementwise_fma(ovd, c1v, b1v);
        Pp[4 * j + 2] = __builtin_elementwise_fma(ovd, c2v, b2v);
        Pp[4 * j + 3] = __builtin_elementwise_fma(ovd, c3v, b3v);
        asm volatile("" : "+v"(Pp[4 * j + 0]), "+v"(Pp[4 * j + 1]),
                          "+v"(Pp[4 * j + 2]), "+v"(Pp[4 * j + 3]));
    }

    hf2 u0 = dup16(u4a.x), u1 = dup16(u4a.y), u2 = dup16(u4a.z), u3 = dup16(u4a.w);
    hf2 u4 = dup16(u4b.x), u5 = dup16(u4b.y), u6 = dup16(u4b.z), u7 = dup16(u4b.w);
    hf2 w0 = dup16(w4a.x), w1 = dup16(w4a.y), w2 = dup16(w4a.z), w3 = dup16(w4a.w);
    hf2 w4 = dup16(w4b.x), w5 = dup16(w4b.y), w6 = dup16(w4b.z), w7 = dup16(w4b.w);

    float c0 = 0.f, c1 = 0.f, c2 = 0.f, c3 = 0.f;
    float c4 = 0.f, c5 = 0.f, c6 = 0.f, c7 = 0.f;
    const hf2 zero = (hf2)(_Float16)0.f;

#pragma unroll
    for (int mp = 0; mp < MHH / 2; ++mp) {
        const hf2 a = Ap[mp], b = Bp[mp], v = Vp[mp], p = Pp[mp];
        hf2 q0 = __builtin_elementwise_fma(u0, a, p);
        hf2 q1 = __builtin_elementwise_fma(u1, a, p);
        hf2 q2 = __builtin_elementwise_fma(u2, a, p);
        hf2 q3 = __builtin_elementwise_fma(u3, a, p);
        hf2 q4 = __builtin_elementwise_fma(u4, a, p);
        hf2 q5 = __builtin_elementwise_fma(u5, a, p);
        hf2 q6 = __builtin_elementwise_fma(u6, a, p);
        hf2 q7 = __builtin_elementwise_fma(u7, a, p);
        q0 = __builtin_elementwise_fma(w0, b, q0);
        q1 = __builtin_elementwise_fma(w1, b, q1);
        q2 = __builtin_elementwise_fma(w2, b, q2);
        q3 = __builtin_elementwise_fma(w3, b, q3);
        q4 = __builtin_elementwise_fma(w4, b, q4);
        q5 = __builtin_elementwise_fma(w5, b, q5);
        q6 = __builtin_elementwise_fma(w6, b, q6);
        q7 = __builtin_elementwise_fma(w7, b, q7);
        q0 = __builtin_elementwise_max(q0, zero);
        q1 = __builtin_elementwise_max(q1, zero);
        q2 = __builtin_elementwise_max(q2, zero);
        q3 = __builtin_elementwise_max(q3, zero);
        q4 = __builtin_elementwise_max(q4, zero);
        q5 = __builtin_elementwise_max(q5, zero);
        q6 = __builtin_elementwise_max(q6, zero);
        q7 = __builtin_elementwise_max(q7, zero);
        c0 = __builtin_amdgcn_fdot2(q0, v, c0, false);
        c1 = __builtin_amdgcn_fdot2(q1, v, c1, false);
        c2 = __builtin_amdgcn_fdot2(q2, v, c2, false);
        c3 = __builtin_amdgcn_fdot2(q3, v, c3, false);
        c4 = __builtin_amdgcn_fdot2(q4, v, c4, false);
        c5 = __builtin_amdgcn_fdot2(q5, v, c5, false);
        c6 = __builtin_amdgcn_fdot2(q6, v, c6, false);
        c7 = __builtin_amdgcn_fdot2(q7, v, c7, false);
    }

    float4 r0, r1;
    r0.x = c0 + bias2; r0.y = c1 + bias2; r0.z = c2 + bias2; r0.w = c3 + bias2;
    r1.x = c4 + bias2; r1.y = c5 + bias2; r1.z = c6 + bias2; r1.w = c7 + bias2;
    *reinterpret_cast<float4*>(nWr + col0) = r0;
    *reinterpret_cast<float4*>(nWr + col1) = r1;
}

// k1: gemv layer1 (blocks 0..511) + constant-packing block (block 512).
__global__ __launch_bounds__(256) void gemv_relu_prep_k(const float* __restrict__ W,
                                                        const float* __restrict__ x,
                                                        const float* __restrict__ b,
                                                        float* __restrict__ y,
                                                        const float* __restrict__ Wm1,
                                                        const float* __restrict__ bm1,
                                                        const float* __restrict__ Wm2,
                                                        unsigned* __restrict__ cst) {
    if (blockIdx.x == DD / 4) {
        const int mp = threadIdx.x;
        if (mp < MHH / 2) {
            const int m = 2 * mp;
            cst[mp]      = pack_pair(Wm1[m],           Wm1[m + 1]);            // A
            cst[16 + mp] = pack_pair(Wm1[MHH + m],     Wm1[MHH + m + 1]);      // B
            cst[32 + mp] = pack_pair(Wm2[m],           Wm2[m + 1]);            // V2
            cst[48 + mp] = pack_pair(Wm1[2 * MHH + m], Wm1[2 * MHH + m + 1]);  // C
            cst[64 + mp] = pack_pair(bm1[m],           bm1[m + 1]);            // bm1
        }
        return;
    }
    gemv4_body(W, x, b, y, blockIdx.x);
}

// k2/k3: combined dispatch — gemv for the NEXT layer (blocks 0..511, memory-
// bound, finishes early) overlapped with meta for the PREVIOUS layer (blocks
// 512..2559, VALU-bound). Both read only data ready at dispatch time.
__global__ __launch_bounds__(256) void combo_k(const float* __restrict__ gW,
                                               const float* __restrict__ gx,
                                               const float* __restrict__ gb,
                                               float* __restrict__ gy,
                                               const float* __restrict__ mW,
                                               const float* __restrict__ minp,
                                               const float* __restrict__ mov,
                                               const unsigned* __restrict__ cst,
                                               const float* __restrict__ bm2,
                                               float* __restrict__ mnW) {
    if (blockIdx.x < DD / 4) {
        gemv4_body(gW, gx, gb, gy, blockIdx.x);
        return;
    }
    const int row = blockIdx.x - DD / 4;
    meta_row_body(mW + (size_t)row * DD, minp, mov[row], cst, bm2[0],
                  mnW + (size_t)row * DD);
}

// k4: meta for the last layer.
__global__ __launch_bounds__(256) void meta_only_k(const float* __restrict__ mW,
                                                   const float* __restrict__ minp,
                                                   const float* __restrict__ mov,
                                                   const unsigned* __restrict__ cst,
                                                   const float* __restrict__ bm2,
                                                   float* __restrict__ mnW) {
    const int row = blockIdx.x;
    meta_row_body(mW + (size_t)row * DD, minp, mov[row], cst, bm2[0],
                  mnW + (size_t)row * DD);
}

extern "C" void kernel_launch(void* const* d_in, const int* in_sizes, int n_in,
                              void* d_out, int out_size, void* d_ws, size_t ws_size,
                              hipStream_t stream) {
    const float* x   = (const float*)d_in[0];
    const float* W1  = (const float*)d_in[1];
    const float* b1  = (const float*)d_in[2];
    const float* W2  = (const float*)d_in[3];
    const float* b2  = (const float*)d_in[4];
    const float* W3  = (const float*)d_in[5];
    const float* b3  = (const float*)d_in[6];
    const float* Wm1 = (const float*)d_in[7];
    const float* bm1 = (const float*)d_in[8];
    const float* Wm2 = (const float*)d_in[9];
    const float* bm2 = (const float*)d_in[10];

    float* out = (float*)d_out;            // out: [2048]
    float* nW1 = out + DD;                 // nW1|nW2|nW3: 3 x 2048 x 2048
    float* nW2 = nW1 + (size_t)DD * DD;
    float* nW3 = nW2 + (size_t)DD * DD;
    float* a1  = (float*)d_ws;             // [2048]
    float* a2  = a1 + DD;                  // [2048]
    unsigned* cst = (unsigned*)(a2 + DD);  // [80] packed f16x2 constants

    // k1: a1 = relu(W1 x + b1); pack meta constants.
    gemv_relu_prep_k<<<DD / 4 + 1, 256, 0, stream>>>(W1, x, b1, a1, Wm1, bm1, Wm2, cst);
    // k2: a2 = relu(W2 a1 + b2)  ||  nW1 = meta(W1, x, a1)
    combo_k<<<DD / 4 + DD, 256, 0, stream>>>(W2, a1, b2, a2,
                                             W1, x, a1, cst, bm2, nW1);
    // k3: out = relu(W3 a2 + b3)  ||  nW2 = meta(W2, a1, a2)
    combo_k<<<DD / 4 + DD, 256, 0, stream>>>(W3, a2, b3, out,
                                             W2, a1, a2, cst, bm2, nW2);
    // k4: nW3 = meta(W3, a2, out)
    meta_only_k<<<DD, 256, 0, stream>>>(W3, a2, out, cst, bm2, nW3);
}

// Round 9
// 48.426 us; speedup vs baseline: 1.0436x; 1.0436x over previous
//
#include <hip/hip_runtime.h>

#define DD 2048
#define MHH 32

typedef _Float16 hf2 __attribute__((ext_vector_type(2)));

__device__ __forceinline__ unsigned pack_pair(float lo, float hi) {
    hf2 v;
    v.x = (_Float16)lo;
    v.y = (_Float16)hi;
    return __builtin_bit_cast(unsigned, v);
}

__device__ __forceinline__ hf2 rfl2(unsigned u) {
    u = __builtin_amdgcn_readfirstlane(u);     // force SGPR residency
    return __builtin_bit_cast(hf2, u);
}

__device__ __forceinline__ hf2 dup16(float x) {
    hf2 v;
    v.x = (_Float16)x;
    v.y = v.x;
    return v;
}

// ---- gemv: 4 rows per block (one wave per row), y = relu(W x + b) ----
__device__ __forceinline__ void gemv4_body(const float* __restrict__ W,
                                           const float* __restrict__ x,
                                           const float* __restrict__ b,
                                           float* __restrict__ y, int blk) {
    const int wave = threadIdx.x >> 6;
    const int lane = threadIdx.x & 63;
    const int row  = (blk << 2) + wave;
    const float* Wr = W + (size_t)row * DD;
    float acc = 0.f;
#pragma unroll
    for (int it = 0; it < 8; ++it) {
        const int col = ((it << 6) + lane) << 2;       // float4 index, coalesced
        const float4 w4 = *reinterpret_cast<const float4*>(Wr + col);
        const float4 x4 = *reinterpret_cast<const float4*>(x + col);
        acc = fmaf(w4.x, x4.x, acc);
        acc = fmaf(w4.y, x4.y, acc);
        acc = fmaf(w4.z, x4.z, acc);
        acc = fmaf(w4.w, x4.w, acc);
    }
#pragma unroll
    for (int off = 32; off > 0; off >>= 1)
        acc += __shfl_down(acc, off, 64);
    if (lane == 0) {
        const float v = acc + b[row];
        y[row] = fmaxf(v, 0.f);
    }
}

// k1: gemv layer1 (blocks 0..511) + constant-packing block (block 512).
__global__ __launch_bounds__(256) void gemv_relu_prep_k(const float* __restrict__ W,
                                                        const float* __restrict__ x,
                                                        const float* __restrict__ b,
                                                        float* __restrict__ y,
                                                        const float* __restrict__ Wm1,
                                                        const float* __restrict__ bm1,
                                                        const float* __restrict__ Wm2,
                                                        unsigned* __restrict__ cst) {
    if (blockIdx.x == DD / 4) {
        const int mp = threadIdx.x;
        if (mp < MHH / 2) {
            const int m = 2 * mp;
            cst[mp]      = pack_pair(Wm1[m],           Wm1[m + 1]);            // A
            cst[16 + mp] = pack_pair(Wm1[MHH + m],     Wm1[MHH + m + 1]);      // B
            cst[32 + mp] = pack_pair(Wm2[m],           Wm2[m + 1]);            // V2
            cst[48 + mp] = pack_pair(Wm1[2 * MHH + m], Wm1[2 * MHH + m + 1]);  // C
            cst[64 + mp] = pack_pair(bm1[m],           bm1[m + 1]);            // bm1
        }
        return;
    }
    gemv4_body(W, x, b, y, blockIdx.x);
}

__global__ __launch_bounds__(256) void gemv_relu_k(const float* __restrict__ W,
                                                   const float* __restrict__ x,
                                                   const float* __restrict__ b,
                                                   float* __restrict__ y) {
    gemv4_body(W, x, b, y, blockIdx.x);
}

// meta: nW[o,i] = bm2 + sum_m V2[m]*relu(u*A + w*B + P),  P = bm1 + ov*C.
// One 128-thread block per (layer,row); 16 elements per thread.
// f16-packed over m-pairs, f32 accumulation (v_dot2_f32_f16).
// ALL loop-invariant VGPR values (element dups, P) are pinned with asm so the
// compiler cannot sink the conversions into the m-loop (the VGPR=24 allocation
// of the previous round proved it was recomputing dups per iteration).
__global__ __launch_bounds__(128, 4) void meta_k(const float* __restrict__ W1,
                                                 const float* __restrict__ W2,
                                                 const float* __restrict__ W3,
                                                 const float* __restrict__ a0,
                                                 const float* __restrict__ a1,
                                                 const float* __restrict__ a2,
                                                 const float* __restrict__ a3,
                                                 const unsigned* __restrict__ cst,
                                                 const float* __restrict__ bm2,
                                                 float* __restrict__ nW) {
    const int layer = blockIdx.x >> 11;          // 2048 rows per layer
    const int row   = blockIdx.x & (DD - 1);

    const float* W   = (layer == 0) ? W1 : (layer == 1) ? W2 : W3;
    const float* inp = (layer == 0) ? a0 : (layer == 1) ? a1 : a2;
    const float* oup = (layer == 0) ? a1 : (layer == 1) ? a2 : a3;

    const float* Wr  = W  + (size_t)row * DD;
    float*       nWr = nW + (size_t)layer * DD * DD + (size_t)row * DD;

    // 16 elements/thread as 4 coalesced float4 chunks (stride 512 floats).
    float4 w4[4], u4[4];
#pragma unroll
    for (int g = 0; g < 4; ++g) {
        const int col = g * (DD / 4) + threadIdx.x * 4;
        w4[g] = *reinterpret_cast<const float4*>(Wr + col);
        u4[g] = *reinterpret_cast<const float4*>(inp + col);
    }

    // ---- constants: pre-packed pairs ----
    const uint4* c16 = (const uint4*)cst;
    hf2 Ap[MHH / 2], Bp[MHH / 2], Vp[MHH / 2], Pp[MHH / 2];
#pragma unroll
    for (int j = 0; j < 4; ++j) {               // A: SGPR
        const uint4 t = c16[j];
        Ap[4 * j + 0] = rfl2(t.x); Ap[4 * j + 1] = rfl2(t.y);
        Ap[4 * j + 2] = rfl2(t.z); Ap[4 * j + 3] = rfl2(t.w);
    }
#pragma unroll
    for (int j = 0; j < 4; ++j) {               // B: SGPR
        const uint4 t = c16[4 + j];
        Bp[4 * j + 0] = rfl2(t.x); Bp[4 * j + 1] = rfl2(t.y);
        Bp[4 * j + 2] = rfl2(t.z); Bp[4 * j + 3] = rfl2(t.w);
    }
#pragma unroll
    for (int j = 0; j < 4; ++j) {               // V2: SGPR
        const uint4 t = c16[8 + j];
        Vp[4 * j + 0] = rfl2(t.x); Vp[4 * j + 1] = rfl2(t.y);
        Vp[4 * j + 2] = rfl2(t.z); Vp[4 * j + 3] = rfl2(t.w);
    }
    const float ov = oup[row];
    const hf2 ovd = dup16(ov);
#pragma unroll
    for (int j = 0; j < 4; ++j) {               // P = bm1 + ov*C, pinned VGPR
        const uint4 tc = c16[12 + j];           // C (-> SGPR)
        const uint4 tb = c16[16 + j];           // bm1 (stays VGPR)
        const hf2 c0v = rfl2(tc.x), c1v = rfl2(tc.y), c2v = rfl2(tc.z), c3v = rfl2(tc.w);
        hf2 b0v = __builtin_bit_cast(hf2, tb.x);
        hf2 b1v = __builtin_bit_cast(hf2, tb.y);
        hf2 b2v = __builtin_bit_cast(hf2, tb.z);
        hf2 b3v = __builtin_bit_cast(hf2, tb.w);
        Pp[4 * j + 0] = __builtin_elementwise_fma(ovd, c0v, b0v);
        Pp[4 * j + 1] = __builtin_elementwise_fma(ovd, c1v, b1v);
        Pp[4 * j + 2] = __builtin_elementwise_fma(ovd, c2v, b2v);
        Pp[4 * j + 3] = __builtin_elementwise_fma(ovd, c3v, b3v);
        asm volatile("" : "+v"(Pp[4 * j + 0]), "+v"(Pp[4 * j + 1]),
                          "+v"(Pp[4 * j + 2]), "+v"(Pp[4 * j + 3]));
    }

    // Element dups, pinned so the cvt/pack is NOT re-done inside the m-loop.
    hf2 ud[16], wd[16];
#pragma unroll
    for (int g = 0; g < 4; ++g) {
        ud[4 * g + 0] = dup16(u4[g].x); ud[4 * g + 1] = dup16(u4[g].y);
        ud[4 * g + 2] = dup16(u4[g].z); ud[4 * g + 3] = dup16(u4[g].w);
        wd[4 * g + 0] = dup16(w4[g].x); wd[4 * g + 1] = dup16(w4[g].y);
        wd[4 * g + 2] = dup16(w4[g].z); wd[4 * g + 3] = dup16(w4[g].w);
        asm volatile("" : "+v"(ud[4 * g + 0]), "+v"(ud[4 * g + 1]),
                          "+v"(ud[4 * g + 2]), "+v"(ud[4 * g + 3]),
                          "+v"(wd[4 * g + 0]), "+v"(wd[4 * g + 1]),
                          "+v"(wd[4 * g + 2]), "+v"(wd[4 * g + 3]));
    }

    const float bias2 = bm2[0];
    float acc[16];
#pragma unroll
    for (int e = 0; e < 16; ++e) acc[e] = bias2;   // fold bias into init
    const hf2 zero = (hf2)(_Float16)0.f;

#pragma unroll
    for (int mp = 0; mp < MHH / 2; ++mp) {
        const hf2 a = Ap[mp], b = Bp[mp], v = Vp[mp], p = Pp[mp];
        hf2 q[16];
#pragma unroll
        for (int e = 0; e < 16; ++e) q[e] = __builtin_elementwise_fma(ud[e], a, p);
#pragma unroll
        for (int e = 0; e < 16; ++e) q[e] = __builtin_elementwise_fma(wd[e], b, q[e]);
#pragma unroll
        for (int e = 0; e < 16; ++e) q[e] = __builtin_elementwise_max(q[e], zero);
#pragma unroll
        for (int e = 0; e < 16; ++e) acc[e] = __builtin_amdgcn_fdot2(q[e], v, acc[e], false);
    }

#pragma unroll
    for (int g = 0; g < 4; ++g) {
        const int col = g * (DD / 4) + threadIdx.x * 4;
        float4 r;
        r.x = acc[4 * g + 0]; r.y = acc[4 * g + 1];
        r.z = acc[4 * g + 2]; r.w = acc[4 * g + 3];
        *reinterpret_cast<float4*>(nWr + col) = r;
    }
}

extern "C" void kernel_launch(void* const* d_in, const int* in_sizes, int n_in,
                              void* d_out, int out_size, void* d_ws, size_t ws_size,
                              hipStream_t stream) {
    const float* x   = (const float*)d_in[0];
    const float* W1  = (const float*)d_in[1];
    const float* b1  = (const float*)d_in[2];
    const float* W2  = (const float*)d_in[3];
    const float* b2  = (const float*)d_in[4];
    const float* W3  = (const float*)d_in[5];
    const float* b3  = (const float*)d_in[6];
    const float* Wm1 = (const float*)d_in[7];
    const float* bm1 = (const float*)d_in[8];
    const float* Wm2 = (const float*)d_in[9];
    const float* bm2 = (const float*)d_in[10];

    float* out = (float*)d_out;            // out: [2048]
    float* nW  = out + DD;                 // nW1|nW2|nW3: 3 x 2048 x 2048
    float* a1  = (float*)d_ws;             // [2048]
    float* a2  = a1 + DD;                  // [2048]
    unsigned* cst = (unsigned*)(a2 + DD);  // [80] packed f16x2 constants

    gemv_relu_prep_k<<<DD / 4 + 1, 256, 0, stream>>>(W1, x, b1, a1, Wm1, bm1, Wm2, cst);
    gemv_relu_k<<<DD / 4, 256, 0, stream>>>(W2, a1, b2, a2);
    gemv_relu_k<<<DD / 4, 256, 0, stream>>>(W3, a2, b3, out);
    meta_k<<<3 * DD, 128, 0, stream>>>(W1, W2, W3, x, a1, a2, out,
                                       cst, bm2, nW);
}

// Round 10
// 46.528 us; speedup vs baseline: 1.0862x; 1.0408x over previous
//
#include <hip/hip_runtime.h>

#define DD 2048
#define MHH 32

typedef _Float16 hf2 __attribute__((ext_vector_type(2)));

__device__ __forceinline__ unsigned pack_pair(float lo, float hi) {
    hf2 v;
    v.x = (_Float16)lo;
    v.y = (_Float16)hi;
    return __builtin_bit_cast(unsigned, v);
}

__device__ __forceinline__ hf2 rfl2(unsigned u) {
    u = __builtin_amdgcn_readfirstlane(u);     // force SGPR residency
    return __builtin_bit_cast(hf2, u);
}

__device__ __forceinline__ hf2 dup16(float x) {
    hf2 v;
    v.x = (_Float16)x;
    v.y = v.x;
    return v;
}

// ---- gemv: 4 rows per block (one wave per row), y = relu(W x + b) ----
__device__ __forceinline__ void gemv4_body(const float* __restrict__ W,
                                           const float* __restrict__ x,
                                           const float* __restrict__ b,
                                           float* __restrict__ y, int blk) {
    const int wave = threadIdx.x >> 6;
    const int lane = threadIdx.x & 63;
    const int row  = (blk << 2) + wave;
    const float* Wr = W + (size_t)row * DD;
    float acc = 0.f;
#pragma unroll
    for (int it = 0; it < 8; ++it) {
        const int col = ((it << 6) + lane) << 2;       // float4 index, coalesced
        const float4 w4 = *reinterpret_cast<const float4*>(Wr + col);
        const float4 x4 = *reinterpret_cast<const float4*>(x + col);
        acc = fmaf(w4.x, x4.x, acc);
        acc = fmaf(w4.y, x4.y, acc);
        acc = fmaf(w4.z, x4.z, acc);
        acc = fmaf(w4.w, x4.w, acc);
    }
#pragma unroll
    for (int off = 32; off > 0; off >>= 1)
        acc += __shfl_down(acc, off, 64);
    if (lane == 0) {
        const float v = acc + b[row];
        y[row] = fmaxf(v, 0.f);
    }
}

// k1: gemv layer1 (blocks 0..511) + constant-packing block (block 512).
__global__ __launch_bounds__(256) void gemv_relu_prep_k(const float* __restrict__ W,
                                                        const float* __restrict__ x,
                                                        const float* __restrict__ b,
                                                        float* __restrict__ y,
                                                        const float* __restrict__ Wm1,
                                                        const float* __restrict__ bm1,
                                                        const float* __restrict__ Wm2,
                                                        unsigned* __restrict__ cst) {
    if (blockIdx.x == DD / 4) {
        const int mp = threadIdx.x;
        if (mp < MHH / 2) {
            const int m = 2 * mp;
            cst[mp]      = pack_pair(Wm1[m],           Wm1[m + 1]);            // A
            cst[16 + mp] = pack_pair(Wm1[MHH + m],     Wm1[MHH + m + 1]);      // B
            cst[32 + mp] = pack_pair(Wm2[m],           Wm2[m + 1]);            // V2
            cst[48 + mp] = pack_pair(Wm1[2 * MHH + m], Wm1[2 * MHH + m + 1]);  // C
            cst[64 + mp] = pack_pair(bm1[m],           bm1[m + 1]);            // bm1
        }
        return;
    }
    gemv4_body(W, x, b, y, blockIdx.x);
}

__global__ __launch_bounds__(256) void gemv_relu_k(const float* __restrict__ W,
                                                   const float* __restrict__ x,
                                                   const float* __restrict__ b,
                                                   float* __restrict__ y) {
    gemv4_body(W, x, b, y, blockIdx.x);
}

// One row's meta compute: given pre-dup'd input (ud), W-row float4s, per-row P,
// accumulate bm2 + sum_m V2[m]*relu(u*A + w*B + P) and store.
__device__ __forceinline__ void meta_row(const float4 w4a, const float4 w4b,
                                         const hf2* __restrict__ ud,
                                         const hf2* __restrict__ Ap,
                                         const hf2* __restrict__ Bp,
                                         const hf2* __restrict__ Vp,
                                         const hf2* __restrict__ Pp,
                                         const float bias2,
                                         float* __restrict__ nWr,
                                         const int col0, const int col1) {
    hf2 wd[8];
    wd[0] = dup16(w4a.x); wd[1] = dup16(w4a.y); wd[2] = dup16(w4a.z); wd[3] = dup16(w4a.w);
    wd[4] = dup16(w4b.x); wd[5] = dup16(w4b.y); wd[6] = dup16(w4b.z); wd[7] = dup16(w4b.w);

    float c0 = 0.f, c1 = 0.f, c2 = 0.f, c3 = 0.f;
    float c4 = 0.f, c5 = 0.f, c6 = 0.f, c7 = 0.f;
    const hf2 zero = (hf2)(_Float16)0.f;

#pragma unroll
    for (int mp = 0; mp < MHH / 2; ++mp) {
        const hf2 a = Ap[mp], b = Bp[mp], v = Vp[mp], p = Pp[mp];
        hf2 q0 = __builtin_elementwise_fma(ud[0], a, p);
        hf2 q1 = __builtin_elementwise_fma(ud[1], a, p);
        hf2 q2 = __builtin_elementwise_fma(ud[2], a, p);
        hf2 q3 = __builtin_elementwise_fma(ud[3], a, p);
        hf2 q4 = __builtin_elementwise_fma(ud[4], a, p);
        hf2 q5 = __builtin_elementwise_fma(ud[5], a, p);
        hf2 q6 = __builtin_elementwise_fma(ud[6], a, p);
        hf2 q7 = __builtin_elementwise_fma(ud[7], a, p);
        q0 = __builtin_elementwise_fma(wd[0], b, q0);
        q1 = __builtin_elementwise_fma(wd[1], b, q1);
        q2 = __builtin_elementwise_fma(wd[2], b, q2);
        q3 = __builtin_elementwise_fma(wd[3], b, q3);
        q4 = __builtin_elementwise_fma(wd[4], b, q4);
        q5 = __builtin_elementwise_fma(wd[5], b, q5);
        q6 = __builtin_elementwise_fma(wd[6], b, q6);
        q7 = __builtin_elementwise_fma(wd[7], b, q7);
        q0 = __builtin_elementwise_max(q0, zero);
        q1 = __builtin_elementwise_max(q1, zero);
        q2 = __builtin_elementwise_max(q2, zero);
        q3 = __builtin_elementwise_max(q3, zero);
        q4 = __builtin_elementwise_max(q4, zero);
        q5 = __builtin_elementwise_max(q5, zero);
        q6 = __builtin_elementwise_max(q6, zero);
        q7 = __builtin_elementwise_max(q7, zero);
        c0 = __builtin_amdgcn_fdot2(q0, v, c0, false);
        c1 = __builtin_amdgcn_fdot2(q1, v, c1, false);
        c2 = __builtin_amdgcn_fdot2(q2, v, c2, false);
        c3 = __builtin_amdgcn_fdot2(q3, v, c3, false);
        c4 = __builtin_amdgcn_fdot2(q4, v, c4, false);
        c5 = __builtin_amdgcn_fdot2(q5, v, c5, false);
        c6 = __builtin_amdgcn_fdot2(q6, v, c6, false);
        c7 = __builtin_amdgcn_fdot2(q7, v, c7, false);
    }

    float4 r0, r1;
    r0.x = c0 + bias2; r0.y = c1 + bias2; r0.z = c2 + bias2; r0.w = c3 + bias2;
    r1.x = c4 + bias2; r1.y = c5 + bias2; r1.z = c6 + bias2; r1.w = c7 + bias2;
    *reinterpret_cast<float4*>(nWr + col0) = r0;
    *reinterpret_cast<float4*>(nWr + col1) = r1;
}

// meta: TWO rows per 256-thread block (3072 blocks total). W-row loads for
// both rows are issued up front (row-1 latency hides under row-0 compute);
// input loads/dups and constant setup are shared across the two rows.
__global__ __launch_bounds__(256) void meta_k(const float* __restrict__ W1,
                                              const float* __restrict__ W2,
                                              const float* __restrict__ W3,
                                              const float* __restrict__ a0,
                                              const float* __restrict__ a1,
                                              const float* __restrict__ a2,
                                              const float* __restrict__ a3,
                                              const unsigned* __restrict__ cst,
                                              const float* __restrict__ bm2,
                                              float* __restrict__ nW) {
    const int layer = blockIdx.x >> 10;          // 1024 row-groups per layer
    const int rgrp  = blockIdx.x & 1023;
    const int row0  = rgrp << 1;                 // two consecutive rows

    const float* W   = (layer == 0) ? W1 : (layer == 1) ? W2 : W3;
    const float* inp = (layer == 0) ? a0 : (layer == 1) ? a1 : a2;
    const float* oup = (layer == 0) ? a1 : (layer == 1) ? a2 : a3;

    const float* Wr0 = W + (size_t)row0 * DD;
    const float* Wr1 = Wr0 + DD;
    float* nWr0 = nW + (size_t)layer * DD * DD + (size_t)row0 * DD;
    float* nWr1 = nWr0 + DD;

    const int col0 = threadIdx.x * 4;            // first half, coalesced float4
    const int col1 = (DD / 2) + threadIdx.x * 4; // second half

    // Issue ALL global loads up front: both W rows, the shared input, ov pair.
    const float4 w0a = *reinterpret_cast<const float4*>(Wr0 + col0);
    const float4 w0b = *reinterpret_cast<const float4*>(Wr0 + col1);
    const float4 w1a = *reinterpret_cast<const float4*>(Wr1 + col0);
    const float4 w1b = *reinterpret_cast<const float4*>(Wr1 + col1);
    const float4 u4a = *reinterpret_cast<const float4*>(inp + col0);
    const float4 u4b = *reinterpret_cast<const float4*>(inp + col1);
    const float2 ovv = *reinterpret_cast<const float2*>(oup + row0);

    // ---- constants: pre-packed pairs (shared across both rows) ----
    const uint4* c16 = (const uint4*)cst;
    hf2 Ap[MHH / 2], Bp[MHH / 2], Vp[MHH / 2];
    hf2 Cm[MHH / 2], Bm[MHH / 2];
#pragma unroll
    for (int j = 0; j < 4; ++j) {               // A: SGPR
        const uint4 t = c16[j];
        Ap[4 * j + 0] = rfl2(t.x); Ap[4 * j + 1] = rfl2(t.y);
        Ap[4 * j + 2] = rfl2(t.z); Ap[4 * j + 3] = rfl2(t.w);
    }
#pragma unroll
    for (int j = 0; j < 4; ++j) {               // B: SGPR
        const uint4 t = c16[4 + j];
        Bp[4 * j + 0] = rfl2(t.x); Bp[4 * j + 1] = rfl2(t.y);
        Bp[4 * j + 2] = rfl2(t.z); Bp[4 * j + 3] = rfl2(t.w);
    }
#pragma unroll
    for (int j = 0; j < 4; ++j) {               // V2: SGPR
        const uint4 t = c16[8 + j];
        Vp[4 * j + 0] = rfl2(t.x); Vp[4 * j + 1] = rfl2(t.y);
        Vp[4 * j + 2] = rfl2(t.z); Vp[4 * j + 3] = rfl2(t.w);
    }
#pragma unroll
    for (int j = 0; j < 4; ++j) {               // C: SGPR, bm1: VGPR
        const uint4 tc = c16[12 + j];
        const uint4 tb = c16[16 + j];
        Cm[4 * j + 0] = rfl2(tc.x); Cm[4 * j + 1] = rfl2(tc.y);
        Cm[4 * j + 2] = rfl2(tc.z); Cm[4 * j + 3] = rfl2(tc.w);
        Bm[4 * j + 0] = __builtin_bit_cast(hf2, tb.x);
        Bm[4 * j + 1] = __builtin_bit_cast(hf2, tb.y);
        Bm[4 * j + 2] = __builtin_bit_cast(hf2, tb.z);
        Bm[4 * j + 3] = __builtin_bit_cast(hf2, tb.w);
    }
    const float bias2 = bm2[0];

    // Shared input dups.
    hf2 ud[8];
    ud[0] = dup16(u4a.x); ud[1] = dup16(u4a.y); ud[2] = dup16(u4a.z); ud[3] = dup16(u4a.w);
    ud[4] = dup16(u4b.x); ud[5] = dup16(u4b.y); ud[6] = dup16(u4b.z); ud[7] = dup16(u4b.w);

    // ---- row 0 ----
    {
        const hf2 ovd = dup16(ovv.x);
        hf2 Pp[MHH / 2];
#pragma unroll
        for (int mp = 0; mp < MHH / 2; ++mp) {
            Pp[mp] = __builtin_elementwise_fma(ovd, Cm[mp], Bm[mp]);
            asm volatile("" : "+v"(Pp[mp]));    // keep P in VGPR
        }
        meta_row(w0a, w0b, ud, Ap, Bp, Vp, Pp, bias2, nWr0, col0, col1);
    }
    // ---- row 1 ----
    {
        const hf2 ovd = dup16(ovv.y);
        hf2 Pp[MHH / 2];
#pragma unroll
        for (int mp = 0; mp < MHH / 2; ++mp) {
            Pp[mp] = __builtin_elementwise_fma(ovd, Cm[mp], Bm[mp]);
            asm volatile("" : "+v"(Pp[mp]));
        }
        meta_row(w1a, w1b, ud, Ap, Bp, Vp, Pp, bias2, nWr1, col0, col1);
    }
}

extern "C" void kernel_launch(void* const* d_in, const int* in_sizes, int n_in,
                              void* d_out, int out_size, void* d_ws, size_t ws_size,
                              hipStream_t stream) {
    const float* x   = (const float*)d_in[0];
    const float* W1  = (const float*)d_in[1];
    const float* b1  = (const float*)d_in[2];
    const float* W2  = (const float*)d_in[3];
    const float* b2  = (const float*)d_in[4];
    const float* W3  = (const float*)d_in[5];
    const float* b3  = (const float*)d_in[6];
    const float* Wm1 = (const float*)d_in[7];
    const float* bm1 = (const float*)d_in[8];
    const float* Wm2 = (const float*)d_in[9];
    const float* bm2 = (const float*)d_in[10];

    float* out = (float*)d_out;            // out: [2048]
    float* nW  = out + DD;                 // nW1|nW2|nW3: 3 x 2048 x 2048
    float* a1  = (float*)d_ws;             // [2048]
    float* a2  = a1 + DD;                  // [2048]
    unsigned* cst = (unsigned*)(a2 + DD);  // [80] packed f16x2 constants

    gemv_relu_prep_k<<<DD / 4 + 1, 256, 0, stream>>>(W1, x, b1, a1, Wm1, bm1, Wm2, cst);
    gemv_relu_k<<<DD / 4, 256, 0, stream>>>(W2, a1, b2, a2);
    gemv_relu_k<<<DD / 4, 256, 0, stream>>>(W3, a2, b3, out);
    meta_k<<<3 * DD / 2, 256, 0, stream>>>(W1, W2, W3, x, a1, a2, out,
                                           cst, bm2, nW);
}

// Round 11
// 45.342 us; speedup vs baseline: 1.1146x; 1.0261x over previous
//
#include <hip/hip_runtime.h>

#define DD 2048
#define MHH 32

typedef _Float16 hf2 __attribute__((ext_vector_type(2)));

__device__ __forceinline__ unsigned pack_pair(float lo, float hi) {
    hf2 v;
    v.x = (_Float16)lo;
    v.y = (_Float16)hi;
    return __builtin_bit_cast(unsigned, v);
}

__device__ __forceinline__ hf2 rfl2(unsigned u) {
    u = __builtin_amdgcn_readfirstlane(u);     // force SGPR residency
    return __builtin_bit_cast(hf2, u);
}

__device__ __forceinline__ hf2 dup16(float x) {
    hf2 v;
    v.x = (_Float16)x;
    v.y = v.x;
    return v;
}

// ---- gemv: 4 rows per block (one wave per row), y = relu(W x + b) ----
__device__ __forceinline__ void gemv4_body(const float* __restrict__ W,
                                           const float* __restrict__ x,
                                           const float* __restrict__ b,
                                           float* __restrict__ y, int blk) {
    const int wave = threadIdx.x >> 6;
    const int lane = threadIdx.x & 63;
    const int row  = (blk << 2) + wave;
    const float* Wr = W + (size_t)row * DD;
    float acc = 0.f;
#pragma unroll
    for (int it = 0; it < 8; ++it) {
        const int col = ((it << 6) + lane) << 2;       // float4 index, coalesced
        const float4 w4 = *reinterpret_cast<const float4*>(Wr + col);
        const float4 x4 = *reinterpret_cast<const float4*>(x + col);
        acc = fmaf(w4.x, x4.x, acc);
        acc = fmaf(w4.y, x4.y, acc);
        acc = fmaf(w4.z, x4.z, acc);
        acc = fmaf(w4.w, x4.w, acc);
    }
#pragma unroll
    for (int off = 32; off > 0; off >>= 1)
        acc += __shfl_down(acc, off, 64);
    if (lane == 0) {
        const float v = acc + b[row];
        y[row] = fmaxf(v, 0.f);
    }
}

// k1: gemv layer1 (blocks 0..511) + constant-packing block (block 512).
__global__ __launch_bounds__(256) void gemv_relu_prep_k(const float* __restrict__ W,
                                                        const float* __restrict__ x,
                                                        const float* __restrict__ b,
                                                        float* __restrict__ y,
                                                        const float* __restrict__ Wm1,
                                                        const float* __restrict__ bm1,
                                                        const float* __restrict__ Wm2,
                                                        unsigned* __restrict__ cst) {
    if (blockIdx.x == DD / 4) {
        const int mp = threadIdx.x;
        if (mp < MHH / 2) {
            const int m = 2 * mp;
            cst[mp]      = pack_pair(Wm1[m],           Wm1[m + 1]);            // A
            cst[16 + mp] = pack_pair(Wm1[MHH + m],     Wm1[MHH + m + 1]);      // B
            cst[32 + mp] = pack_pair(Wm2[m],           Wm2[m + 1]);            // V2
            cst[48 + mp] = pack_pair(Wm1[2 * MHH + m], Wm1[2 * MHH + m + 1]);  // C
            cst[64 + mp] = pack_pair(bm1[m],           bm1[m + 1]);            // bm1
        }
        return;
    }
    gemv4_body(W, x, b, y, blockIdx.x);
}

__global__ __launch_bounds__(256) void gemv_relu_k(const float* __restrict__ W,
                                                   const float* __restrict__ x,
                                                   const float* __restrict__ b,
                                                   float* __restrict__ y) {
    gemv4_body(W, x, b, y, blockIdx.x);
}

// meta: 1536 blocks (512 per layer), each block = FOUR consecutive rows of one
// layer. All blocks co-resident (6 blocks/CU at <=85 VGPR): constant setup,
// input load+dup done ONCE per block; per-row cost is 2 W float4 loads,
// 16 P-fmas, and the 512-instr packed inner loop.
__global__ __launch_bounds__(256, 6) void meta_k(const float* __restrict__ W1,
                                                 const float* __restrict__ W2,
                                                 const float* __restrict__ W3,
                                                 const float* __restrict__ a0,
                                                 const float* __restrict__ a1,
                                                 const float* __restrict__ a2,
                                                 const float* __restrict__ a3,
                                                 const unsigned* __restrict__ cst,
                                                 const float* __restrict__ bm2,
                                                 float* __restrict__ nW) {
    const int layer = blockIdx.x >> 9;           // 512 blocks per layer
    const int row0  = (blockIdx.x & 511) << 2;   // 4 consecutive rows

    const float* W   = (layer == 0) ? W1 : (layer == 1) ? W2 : W3;
    const float* inp = (layer == 0) ? a0 : (layer == 1) ? a1 : a2;
    const float* oup = (layer == 0) ? a1 : (layer == 1) ? a2 : a3;

    const float* Wr  = W  + (size_t)row0 * DD;
    float*       nWr = nW + (size_t)layer * DD * DD + (size_t)row0 * DD;

    const int col0 = threadIdx.x * 4;            // first half, coalesced float4
    const int col1 = (DD / 2) + threadIdx.x * 4; // second half

    // Shared (per-block) loads: input vector halves + the 4 output activations.
    const float4 u4a = *reinterpret_cast<const float4*>(inp + col0);
    const float4 u4b = *reinterpret_cast<const float4*>(inp + col1);
    const float4 ov4 = *reinterpret_cast<const float4*>(oup + row0);

    // ---- constants: A/B/V2/C -> SGPR, bm1 -> VGPR (once per block) ----
    const uint4* c16 = (const uint4*)cst;
    hf2 Ap[MHH / 2], Bp[MHH / 2], Vp[MHH / 2], Cm[MHH / 2], Bm[MHH / 2];
#pragma unroll
    for (int j = 0; j < 4; ++j) {
        const uint4 t = c16[j];
        Ap[4 * j + 0] = rfl2(t.x); Ap[4 * j + 1] = rfl2(t.y);
        Ap[4 * j + 2] = rfl2(t.z); Ap[4 * j + 3] = rfl2(t.w);
    }
#pragma unroll
    for (int j = 0; j < 4; ++j) {
        const uint4 t = c16[4 + j];
        Bp[4 * j + 0] = rfl2(t.x); Bp[4 * j + 1] = rfl2(t.y);
        Bp[4 * j + 2] = rfl2(t.z); Bp[4 * j + 3] = rfl2(t.w);
    }
#pragma unroll
    for (int j = 0; j < 4; ++j) {
        const uint4 t = c16[8 + j];
        Vp[4 * j + 0] = rfl2(t.x); Vp[4 * j + 1] = rfl2(t.y);
        Vp[4 * j + 2] = rfl2(t.z); Vp[4 * j + 3] = rfl2(t.w);
    }
#pragma unroll
    for (int j = 0; j < 4; ++j) {
        const uint4 tc = c16[12 + j];
        const uint4 tb = c16[16 + j];
        Cm[4 * j + 0] = rfl2(tc.x); Cm[4 * j + 1] = rfl2(tc.y);
        Cm[4 * j + 2] = rfl2(tc.z); Cm[4 * j + 3] = rfl2(tc.w);
        Bm[4 * j + 0] = __builtin_bit_cast(hf2, tb.x);
        Bm[4 * j + 1] = __builtin_bit_cast(hf2, tb.y);
        Bm[4 * j + 2] = __builtin_bit_cast(hf2, tb.z);
        Bm[4 * j + 3] = __builtin_bit_cast(hf2, tb.w);
    }
    const float bias2 = bm2[0];

    // Shared input dups (pinned — invariant across all 4 rows and the m-loop).
    hf2 ud[8];
    ud[0] = dup16(u4a.x); ud[1] = dup16(u4a.y); ud[2] = dup16(u4a.z); ud[3] = dup16(u4a.w);
    ud[4] = dup16(u4b.x); ud[5] = dup16(u4b.y); ud[6] = dup16(u4b.z); ud[7] = dup16(u4b.w);
    asm volatile("" : "+v"(ud[0]), "+v"(ud[1]), "+v"(ud[2]), "+v"(ud[3]),
                      "+v"(ud[4]), "+v"(ud[5]), "+v"(ud[6]), "+v"(ud[7]));

    const hf2 zero = (hf2)(_Float16)0.f;

#pragma unroll
    for (int r = 0; r < 4; ++r) {
        const float* Wrr = Wr + (size_t)r * DD;
        const float4 wa = *reinterpret_cast<const float4*>(Wrr + col0);
        const float4 wb = *reinterpret_cast<const float4*>(Wrr + col1);
        const float ovr = (r == 0) ? ov4.x : (r == 1) ? ov4.y : (r == 2) ? ov4.z : ov4.w;
        const hf2 ovd = dup16(ovr);

        hf2 Pp[MHH / 2];
#pragma unroll
        for (int mp = 0; mp < MHH / 2; ++mp) {
            Pp[mp] = __builtin_elementwise_fma(ovd, Cm[mp], Bm[mp]);
            asm volatile("" : "+v"(Pp[mp]));    // keep P in VGPR
        }

        hf2 wd[8];
        wd[0] = dup16(wa.x); wd[1] = dup16(wa.y); wd[2] = dup16(wa.z); wd[3] = dup16(wa.w);
        wd[4] = dup16(wb.x); wd[5] = dup16(wb.y); wd[6] = dup16(wb.z); wd[7] = dup16(wb.w);

        float c0 = bias2, c1 = bias2, c2 = bias2, c3 = bias2;
        float c4 = bias2, c5 = bias2, c6 = bias2, c7 = bias2;

#pragma unroll
        for (int mp = 0; mp < MHH / 2; ++mp) {
            const hf2 a = Ap[mp], b = Bp[mp], v = Vp[mp], p = Pp[mp];
            hf2 q0 = __builtin_elementwise_fma(ud[0], a, p);
            hf2 q1 = __builtin_elementwise_fma(ud[1], a, p);
            hf2 q2 = __builtin_elementwise_fma(ud[2], a, p);
            hf2 q3 = __builtin_elementwise_fma(ud[3], a, p);
            hf2 q4 = __builtin_elementwise_fma(ud[4], a, p);
            hf2 q5 = __builtin_elementwise_fma(ud[5], a, p);
            hf2 q6 = __builtin_elementwise_fma(ud[6], a, p);
            hf2 q7 = __builtin_elementwise_fma(ud[7], a, p);
            q0 = __builtin_elementwise_fma(wd[0], b, q0);
            q1 = __builtin_elementwise_fma(wd[1], b, q1);
            q2 = __builtin_elementwise_fma(wd[2], b, q2);
            q3 = __builtin_elementwise_fma(wd[3], b, q3);
            q4 = __builtin_elementwise_fma(wd[4], b, q4);
            q5 = __builtin_elementwise_fma(wd[5], b, q5);
            q6 = __builtin_elementwise_fma(wd[6], b, q6);
            q7 = __builtin_elementwise_fma(wd[7], b, q7);
            q0 = __builtin_elementwise_max(q0, zero);
            q1 = __builtin_elementwise_max(q1, zero);
            q2 = __builtin_elementwise_max(q2, zero);
            q3 = __builtin_elementwise_max(q3, zero);
            q4 = __builtin_elementwise_max(q4, zero);
            q5 = __builtin_elementwise_max(q5, zero);
            q6 = __builtin_elementwise_max(q6, zero);
            q7 = __builtin_elementwise_max(q7, zero);
            c0 = __builtin_amdgcn_fdot2(q0, v, c0, false);
            c1 = __builtin_amdgcn_fdot2(q1, v, c1, false);
            c2 = __builtin_amdgcn_fdot2(q2, v, c2, false);
            c3 = __builtin_amdgcn_fdot2(q3, v, c3, false);
            c4 = __builtin_amdgcn_fdot2(q4, v, c4, false);
            c5 = __builtin_amdgcn_fdot2(q5, v, c5, false);
            c6 = __builtin_amdgcn_fdot2(q6, v, c6, false);
            c7 = __builtin_amdgcn_fdot2(q7, v, c7, false);
        }

        float4 r0, r1;
        r0.x = c0; r0.y = c1; r0.z = c2; r0.w = c3;
        r1.x = c4; r1.y = c5; r1.z = c6; r1.w = c7;
        float* nWrr = nWr + (size_t)r * DD;
        *reinterpret_cast<float4*>(nWrr + col0) = r0;
        *reinterpret_cast<float4*>(nWrr + col1) = r1;
    }
}

extern "C" void kernel_launch(void* const* d_in, const int* in_sizes, int n_in,
                              void* d_out, int out_size, void* d_ws, size_t ws_size,
                              hipStream_t stream) {
    const float* x   = (const float*)d_in[0];
    const float* W1  = (const float*)d_in[1];
    const float* b1  = (const float*)d_in[2];
    const float* W2  = (const float*)d_in[3];
    const float* b2  = (const float*)d_in[4];
    const float* W3  = (const float*)d_in[5];
    const float* b3  = (const float*)d_in[6];
    const float* Wm1 = (const float*)d_in[7];
    const float* bm1 = (const float*)d_in[8];
    const float* Wm2 = (const float*)d_in[9];
    const float* bm2 = (const float*)d_in[10];

    float* out = (float*)d_out;            // out: [2048]
    float* nW  = out + DD;                 // nW1|nW2|nW3: 3 x 2048 x 2048
    float* a1  = (float*)d_ws;             // [2048]
    float* a2  = a1 + DD;                  // [2048]
    unsigned* cst = (unsigned*)(a2 + DD);  // [80] packed f16x2 constants

    gemv_relu_prep_k<<<DD / 4 + 1, 256, 0, stream>>>(W1, x, b1, a1, Wm1, bm1, Wm2, cst);
    gemv_relu_k<<<DD / 4, 256, 0, stream>>>(W2, a1, b2, a2);
    gemv_relu_k<<<DD / 4, 256, 0, stream>>>(W3, a2, b3, out);
    meta_k<<<3 * DD / 4, 256, 0, stream>>>(W1, W2, W3, x, a1, a2, out,
                                           cst, bm2, nW);
}